// Round 3
// baseline (251.850 us; speedup 1.0000x reference)
//
#include <hip/hip_runtime.h>

typedef __attribute__((ext_vector_type(8))) short short8;
typedef __attribute__((ext_vector_type(4))) float f32x4;

#define CM 256
#define CC 32
#define CZ 128
#define SDIM 128
#define IDIM 256

__device__ __forceinline__ unsigned short f2bf(float f) {
  union { float f; unsigned u; } v; v.f = f;
  unsigned r = v.u + 0x7fffu + ((v.u >> 16) & 1u);
  return (unsigned short)(r >> 16);
}

// ---------------- kernel 0: weight prep ----------------
// wlrT[c64][e]  (c64<32: w_left col, else w_right col), bf16, [64][256]
// WoT[z][kappa] with kappa = d*32 + c, value = w_out[(c*32+d)][z] / 128, bf16, [128][1024]
__global__ void k_prep(const float* __restrict__ wl, const float* __restrict__ wr,
                       const float* __restrict__ wo,
                       unsigned short* __restrict__ wlrT, unsigned short* __restrict__ WoT) {
  int t = blockIdx.x * 256 + threadIdx.x;
  if (t < 64 * 256) {
    int c = t >> 8, e = t & 255;
    float v = (c < CC) ? wl[e * CC + c] : wr[e * CC + (c - CC)];
    wlrT[c * 256 + e] = f2bf(v);
  } else {
    int t2 = t - 64 * 256;
    if (t2 < 128 * 1024) {
      int z = t2 >> 10, kap = t2 & 1023;
      int d = kap >> 5, c = kap & 31;
      WoT[z * 1024 + kap] = f2bf(wo[(c * 32 + d) * CZ + z] * (1.0f / 128.0f));
    }
  }
}

// ---------------- kernel 1: LayerNorm + dual projection ----------------
// 512 blocks x 256 threads; block handles 64 consecutive rows r = s*256+i (same s).
// Outputs Abuf[i*32+c][s], Bbuf[j*32+d][s] as bf16 (K-major for GEMM1 frags).
__global__ __launch_bounds__(256) void k_lnproj(
    const float* __restrict__ x, const float* __restrict__ lnw, const float* __restrict__ lnb,
    const float* __restrict__ bl, const float* __restrict__ br,
    const unsigned short* __restrict__ wlrT,
    unsigned short* __restrict__ Abuf, unsigned short* __restrict__ Bbuf) {
  // ROW = 256 bf16 shorts + 8 pad = 264 shorts (528 B, 16B-aligned stride).
  // R1 bug: [64][136] sized the row in *shorts* for K=128, but C_M=256 -> rows aliased.
  __shared__ __align__(16) unsigned short xn[64][264];
  int tid = threadIdx.x;
  int lane = tid & 63, ww = tid >> 6;
  int r0 = blockIdx.x * 64;

  for (int rr = 0; rr < 16; ++rr) {
    int rloc = ww * 16 + rr;
    float4 v = ((const float4*)(x + (size_t)(r0 + rloc) * CM))[lane];
    float s1 = v.x + v.y + v.z + v.w;
    float s2 = v.x * v.x + v.y * v.y + v.z * v.z + v.w * v.w;
#pragma unroll
    for (int off = 32; off; off >>= 1) {
      s1 += __shfl_xor(s1, off);
      s2 += __shfl_xor(s2, off);
    }
    float mu = s1 * (1.0f / 256.0f);
    float var = s2 * (1.0f / 256.0f) - mu * mu;
    float rs = rsqrtf(var + 1e-5f);
    float4 w4 = ((const float4*)lnw)[lane];
    float4 b4 = ((const float4*)lnb)[lane];
    ushort4 h;
    h.x = f2bf((v.x - mu) * rs * w4.x + b4.x);
    h.y = f2bf((v.y - mu) * rs * w4.y + b4.y);
    h.z = f2bf((v.z - mu) * rs * w4.z + b4.z);
    h.w = f2bf((v.w - mu) * rs * w4.w + b4.w);
    *(ushort4*)&xn[rloc][lane * 4] = h;
  }
  __syncthreads();

  int qd = lane >> 4, ln = lane & 15;
  f32x4 acc[4];
#pragma unroll
  for (int nt = 0; nt < 4; ++nt) acc[nt] = (f32x4){0.f, 0.f, 0.f, 0.f};
#pragma unroll
  for (int ks = 0; ks < 8; ++ks) {
    short8 af = *(const short8*)&xn[ww * 16 + ln][ks * 32 + qd * 8];
#pragma unroll
    for (int nt = 0; nt < 4; ++nt) {
      short8 bf = *(const short8*)(wlrT + (nt * 16 + ln) * 256 + ks * 32 + qd * 8);
      acc[nt] = __builtin_amdgcn_mfma_f32_16x16x32_bf16(af, bf, acc[nt], 0, 0, 0);
    }
  }
  // C/D layout (16x16): col = lane&15 (=n, channel), row = (lane>>4)*4 + reg (=m, MSA row)
  int s = r0 >> 8;                       // constant per block
  int ib = (r0 & 255) + ww * 16 + qd * 4;
#pragma unroll
  for (int nt = 0; nt < 4; ++nt) {
    int c64 = nt * 16 + ln;
    int isA = (c64 < CC);
    int c = isA ? c64 : (c64 - CC);
    float bias = isA ? bl[c] : br[c];
    unsigned short* dst = isA ? Abuf : Bbuf;
#pragma unroll
    for (int rg = 0; rg < 4; ++rg) {
      int i = ib + rg;
      dst[(i * CC + c) * SDIM + s] = f2bf(acc[nt][rg] + bias);
    }
  }
}

// ---------------- kernel 2: fused outer-product + output projection ----------------
// Block = (8 i-values) x (8 j-values) = 64 pairs -> out tile 64x128.
// Phase 1: P[256][256] = A_tile @ B_tile^T over K=s=128 (16x16x32 MFMA, 4x4 tiles/wave).
// P -> LDS bf16, kappa = d*32+c ordering, 16B-chunk XOR swizzle.
// Phase 2: out[64][128] = P @ WoT^T over K=1024.
__global__ __launch_bounds__(1024) void k_main(
    const unsigned short* __restrict__ Abuf, const unsigned short* __restrict__ Bbuf,
    const unsigned short* __restrict__ WoT, const float* __restrict__ bout,
    float* __restrict__ out) {
  extern __shared__ __align__(16) char lds[];
  unsigned short* sA = (unsigned short*)lds;         // [256][136] bf16 = 69,632 B (K=128+8 pad)
  unsigned short* sB = sA + 256 * 136;               // [256][136] bf16 = 69,632 B
  unsigned short* sP = (unsigned short*)lds;         // [64][1032] bf16 = 132,096 B (overlaps)
  int tid = threadIdx.x;
  int lane = tid & 63, ww = tid >> 6;
  int qd = lane >> 4, ln = lane & 15;
  int i0 = blockIdx.x * 8, j0 = blockIdx.y * 8;

  // stage A/B tiles: rows [i0*32, +256) x K=128, coalesced 16B loads -> padded LDS
  {
    int row = tid >> 4, ch = tid & 15;
#pragma unroll
    for (int it = 0; it < 4; ++it) {
      int r = it * 64 + row;
      short8 va = *(const short8*)(Abuf + (size_t)(i0 * CC + r) * SDIM + ch * 8);
      short8 vb = *(const short8*)(Bbuf + (size_t)(j0 * CC + r) * SDIM + ch * 8);
      *(short8*)&sA[r * 136 + ch * 8] = va;
      *(short8*)&sB[r * 136 + ch * 8] = vb;
    }
  }
  __syncthreads();

  // phase 1: wave (wy,wx) computes 64x64 region = 4x4 tiles of 16x16
  int wy = ww >> 2, wx = ww & 3;
  f32x4 acc1[4][4];
  for (int a = 0; a < 4; ++a)
    for (int b = 0; b < 4; ++b) acc1[a][b] = (f32x4){0.f, 0.f, 0.f, 0.f};
#pragma unroll
  for (int ks = 0; ks < 4; ++ks) {
    short8 af[4];
#pragma unroll
    for (int ti = 0; ti < 4; ++ti)
      af[ti] = *(const short8*)&sA[(wy * 64 + ti * 16 + ln) * 136 + ks * 32 + qd * 8];
#pragma unroll
    for (int tj = 0; tj < 4; ++tj) {
      short8 bf = *(const short8*)&sB[(wx * 64 + tj * 16 + ln) * 136 + ks * 32 + qd * 8];
#pragma unroll
      for (int ti = 0; ti < 4; ++ti)
        acc1[ti][tj] = __builtin_amdgcn_mfma_f32_16x16x32_bf16(af[ti], bf, acc1[ti][tj], 0, 0, 0);
    }
  }
  __syncthreads();  // all staging reads done before P overwrites sA/sB

  // write P: element (pair p, kappa=d*32+c) at shorts offset
  //   p*1032 + d*32 + ((cb8 ^ (d&3))*8) + (c&7),  cb8 = c>>3
#pragma unroll
  for (int ti = 0; ti < 4; ++ti) {
    int m0 = wy * 64 + ti * 16;
    int iloc = m0 >> 5;
    int cbase = (m0 & 31) + qd * 4;      // c for reg 0; regs give c..c+3
    int cb8 = cbase >> 3;
#pragma unroll
    for (int tj = 0; tj < 4; ++tj) {
      int n0 = wx * 64 + tj * 16;
      int jloc = n0 >> 5;
      int d = (n0 & 31) + ln;
      int p = iloc * 8 + jloc;
      ushort4 h;
      h.x = f2bf(acc1[ti][tj][0]);
      h.y = f2bf(acc1[ti][tj][1]);
      h.z = f2bf(acc1[ti][tj][2]);
      h.w = f2bf(acc1[ti][tj][3]);
      *(ushort4*)&sP[p * 1032 + d * 32 + ((cb8 ^ (d & 3)) * 8) + (cbase & 7)] = h;
    }
  }
  __syncthreads();

  // phase 2: M=64 pairs (4 m-tiles), N=128 (8 n-tiles), K=1024 (32 steps; d = ks fixed per step)
  int mt = ww >> 2, nh = ww & 3;
  f32x4 acc2[2];
  acc2[0] = (f32x4){0.f, 0.f, 0.f, 0.f};
  acc2[1] = (f32x4){0.f, 0.f, 0.f, 0.f};
  int prow = mt * 16 + ln;
#pragma unroll 4
  for (int ks = 0; ks < 32; ++ks) {
    short8 af = *(const short8*)&sP[prow * 1032 + ks * 32 + ((qd ^ (ks & 3)) * 8)];
#pragma unroll
    for (int h2 = 0; h2 < 2; ++h2) {
      int zt = nh * 2 + h2;
      short8 bf = *(const short8*)(WoT + (zt * 16 + ln) * 1024 + ks * 32 + qd * 8);
      acc2[h2] = __builtin_amdgcn_mfma_f32_16x16x32_bf16(af, bf, acc2[h2], 0, 0, 0);
    }
  }
  // epilogue: D col = z_local, row = pair_local; p = iloc*8 + jloc
#pragma unroll
  for (int h2 = 0; h2 < 2; ++h2) {
    int z = (nh * 2 + h2) * 16 + ln;
    float bz = bout[z];
#pragma unroll
    for (int rg = 0; rg < 4; ++rg) {
      int p = mt * 16 + qd * 4 + rg;
      int i = i0 + (p >> 3), j = j0 + (p & 7);
      out[((size_t)i * IDIM + j) * CZ + z] = acc2[h2][rg] + bz;
    }
  }
}

extern "C" void kernel_launch(void* const* d_in, const int* in_sizes, int n_in,
                              void* d_out, int out_size, void* d_ws, size_t ws_size,
                              hipStream_t stream) {
  const float* msa = (const float*)d_in[0];
  const float* lnw = (const float*)d_in[1];
  const float* lnb = (const float*)d_in[2];
  const float* wl  = (const float*)d_in[3];
  const float* bl  = (const float*)d_in[4];
  const float* wr  = (const float*)d_in[5];
  const float* br  = (const float*)d_in[6];
  const float* wo  = (const float*)d_in[7];
  const float* bo  = (const float*)d_in[8];
  float* out = (float*)d_out;

  // workspace layout (4.3 MB total)
  char* ws = (char*)d_ws;
  unsigned short* Abuf = (unsigned short*)ws;                         // 2 MB
  unsigned short* Bbuf = (unsigned short*)(ws + (2u << 20));          // 2 MB
  unsigned short* wlrT = (unsigned short*)(ws + (4u << 20));          // 32 KB
  unsigned short* WoT  = (unsigned short*)(ws + (4u << 20) + 32768);  // 256 KB

  (void)hipFuncSetAttribute((const void*)k_main,
                            hipFuncAttributeMaxDynamicSharedMemorySize, 139264);

  k_prep<<<576, 256, 0, stream>>>(wl, wr, wo, wlrT, WoT);
  k_lnproj<<<512, 256, 0, stream>>>(msa, lnw, lnb, bl, br, wlrT, Abuf, Bbuf);
  k_main<<<dim3(32, 32), 1024, 139264, stream>>>(Abuf, Bbuf, WoT, bo, out);
}

// Round 4
// 155.882 us; speedup vs baseline: 1.6156x; 1.6156x over previous
//
#include <hip/hip_runtime.h>

typedef __attribute__((ext_vector_type(8))) short short8;
typedef __attribute__((ext_vector_type(4))) float f32x4;

#define CM 256
#define CC 32
#define CZ 128
#define SDIM 128
#define IDIM 256

__device__ __forceinline__ unsigned short f2bf(float f) {
  union { float f; unsigned u; } v; v.f = f;
  unsigned r = v.u + 0x7fffu + ((v.u >> 16) & 1u);
  return (unsigned short)(r >> 16);
}

// ---------------- kernel 0: weight prep ----------------
// wlrT[c64][e]  (c64<32: w_left col, else w_right col), bf16, [64][256]
// WF = W_out packed fragment-major: WF[((zt*32+ks)*64 + lane)*8 + e]
//   lane=(qd*16+ln) holds WoT_logical[z=zt*16+ln][kappa=ks*32+qd*8+e]
//   WoT_logical[z][kappa] = w_out[(c*32+d)][z]/128 with kappa=d*32+c (d=ks, c=qd*8+e)
__global__ void k_prep(const float* __restrict__ wl, const float* __restrict__ wr,
                       const float* __restrict__ wo,
                       unsigned short* __restrict__ wlrT, unsigned short* __restrict__ WF) {
  int t = blockIdx.x * 256 + threadIdx.x;
  if (t < 64 * 256) {
    int c = t >> 8, e = t & 255;
    float v = (c < CC) ? wl[e * CC + c] : wr[e * CC + (c - CC)];
    wlrT[c * 256 + e] = f2bf(v);
  } else {
    int t2 = t - 64 * 256;
    if (t2 < 8 * 32 * 64) {
      int zt = t2 >> 11, ks = (t2 >> 6) & 31, lane = t2 & 63;
      int ln = lane & 15, qd = lane >> 4;
      int z = zt * 16 + ln;
#pragma unroll
      for (int e = 0; e < 8; ++e) {
        int c = qd * 8 + e, d = ks;
        WF[(size_t)t2 * 8 + e] = f2bf(wo[(c * 32 + d) * CZ + z] * (1.0f / 128.0f));
      }
    }
  }
}

// ---------------- kernel 1: LayerNorm + dual projection ----------------
// One block per i (256 blocks x 512 threads): LN all 128 s-rows of column i,
// MFMA-project (M=128 s, N=64 c64, K=256), transpose C-frags via LDS,
// store Abuf[(i*32+c)][s] / Bbuf[(i*32+d)][s] as coalesced 256-B rows.
__global__ __launch_bounds__(512) void k_lnproj(
    const float* __restrict__ x, const float* __restrict__ lnw, const float* __restrict__ lnb,
    const float* __restrict__ bl, const float* __restrict__ br,
    const unsigned short* __restrict__ wlrT,
    unsigned short* __restrict__ Abuf, unsigned short* __restrict__ Bbuf) {
  extern __shared__ __align__(16) char lds[];
  unsigned short* xn = (unsigned short*)lds;            // [128 s][264] = 67,584 B
  unsigned short* sT = (unsigned short*)(lds + 67584);  // [64 c64][136] = 17,408 B
  int tid = threadIdx.x;
  int lane = tid & 63, ww = tid >> 6;      // 8 waves
  int qd = lane >> 4, ln = lane & 15;
  int i = blockIdx.x;

  // LN: wave ww handles s = ww*16 .. +15
  for (int rr = 0; rr < 16; ++rr) {
    int s = ww * 16 + rr;
    float4 v = ((const float4*)(x + ((size_t)s * IDIM + i) * CM))[lane];
    float s1 = v.x + v.y + v.z + v.w;
    float s2 = v.x * v.x + v.y * v.y + v.z * v.z + v.w * v.w;
#pragma unroll
    for (int off = 32; off; off >>= 1) {
      s1 += __shfl_xor(s1, off);
      s2 += __shfl_xor(s2, off);
    }
    float mu = s1 * (1.0f / 256.0f);
    float var = s2 * (1.0f / 256.0f) - mu * mu;
    float rs = rsqrtf(var + 1e-5f);
    float4 w4 = ((const float4*)lnw)[lane];
    float4 b4 = ((const float4*)lnb)[lane];
    ushort4 h;
    h.x = f2bf((v.x - mu) * rs * w4.x + b4.x);
    h.y = f2bf((v.y - mu) * rs * w4.y + b4.y);
    h.z = f2bf((v.z - mu) * rs * w4.z + b4.z);
    h.w = f2bf((v.w - mu) * rs * w4.w + b4.w);
    *(ushort4*)&xn[s * 264 + lane * 4] = h;
  }
  __syncthreads();

  // project: wave ww = m-tile (16 s-rows), all 4 n-tiles, K=256
  f32x4 acc[4];
#pragma unroll
  for (int nt = 0; nt < 4; ++nt) acc[nt] = (f32x4){0.f, 0.f, 0.f, 0.f};
#pragma unroll
  for (int ks = 0; ks < 8; ++ks) {
    short8 af = *(const short8*)&xn[(ww * 16 + ln) * 264 + ks * 32 + qd * 8];
#pragma unroll
    for (int nt = 0; nt < 4; ++nt) {
      short8 bf = *(const short8*)(wlrT + (nt * 16 + ln) * 256 + ks * 32 + qd * 8);
      acc[nt] = __builtin_amdgcn_mfma_f32_16x16x32_bf16(af, bf, acc[nt], 0, 0, 0);
    }
  }
  // C layout: col(c64)=ln, row(s-local)=qd*4+rg. Add bias, transpose via sT[c64][s].
#pragma unroll
  for (int nt = 0; nt < 4; ++nt) {
    int c64 = nt * 16 + ln;
    float bias = (c64 < CC) ? bl[c64] : br[c64 - CC];
    ushort4 h;
    h.x = f2bf(acc[nt][0] + bias);
    h.y = f2bf(acc[nt][1] + bias);
    h.z = f2bf(acc[nt][2] + bias);
    h.w = f2bf(acc[nt][3] + bias);
    *(ushort4*)&sT[c64 * 136 + ww * 16 + qd * 4] = h;
  }
  __syncthreads();

  // store 64 rows x 256 B coalesced: Abuf[(i*32+c)*128 + s], Bbuf likewise
#pragma unroll
  for (int k = 0; k < 2; ++k) {
    int idx = tid + k * 512;        // 1024 chunks of 16 B
    int row = idx >> 4, ch = idx & 15;
    short8 v = *(const short8*)&sT[row * 136 + ch * 8];
    unsigned short* dst = (row < CC) ? (Abuf + ((size_t)(i * CC + row)) * SDIM)
                                     : (Bbuf + ((size_t)(i * CC + row - CC)) * SDIM);
    *(short8*)(dst + ch * 8) = v;
  }
}

// ---------------- kernel 2: fused outer-product + output projection ----------------
// Block = 8i x 8j = 64 pairs -> out tile 64x128. 1024 threads (16 waves).
// Phase 1: P[256][256] = A_tile @ B_tile^T over K=128 (4x4 frag tiles/wave).
// P -> LDS bf16 (kappa=d*32+c, XOR-swizzled).
// Phase 2: out[64][128] = P @ WF^T over K=1024; wave job = (zt-pair, K-quarter),
//          each wave does all 4 m-tiles -> WF frag loads are 1 KB coalesced, no redundancy.
//          K-quarter partials tree-reduced through LDS (reuses dead sP region).
__global__ __launch_bounds__(1024) void k_main(
    const unsigned short* __restrict__ Abuf, const unsigned short* __restrict__ Bbuf,
    const unsigned short* __restrict__ WF, const float* __restrict__ bout,
    float* __restrict__ out) {
  extern __shared__ __align__(16) char lds[];
  unsigned short* sA = (unsigned short*)lds;         // [256][136] = 69,632 B
  unsigned short* sB = sA + 256 * 136;               // [256][136] = 69,632 B
  unsigned short* sP = (unsigned short*)lds;         // [64][1032] = 132,096 B (overlaps)
  float* redF = (float*)lds;                         // reduction scratch (overlaps, 67.6 KB)
  int tid = threadIdx.x;
  int lane = tid & 63, ww = tid >> 6;
  int qd = lane >> 4, ln = lane & 15;
  int i0 = blockIdx.x * 8, j0 = blockIdx.y * 8;

  // stage A/B tiles (each wave reads 1 KB contiguous per instr)
  {
    int row = tid >> 4, ch = tid & 15;
#pragma unroll
    for (int it = 0; it < 4; ++it) {
      int r = it * 64 + row;
      short8 va = *(const short8*)(Abuf + (size_t)(i0 * CC + r) * SDIM + ch * 8);
      short8 vb = *(const short8*)(Bbuf + (size_t)(j0 * CC + r) * SDIM + ch * 8);
      *(short8*)&sA[r * 136 + ch * 8] = va;
      *(short8*)&sB[r * 136 + ch * 8] = vb;
    }
  }
  __syncthreads();

  // phase 1
  int wy = ww >> 2, wx = ww & 3;
  f32x4 acc1[4][4];
  for (int a = 0; a < 4; ++a)
    for (int b = 0; b < 4; ++b) acc1[a][b] = (f32x4){0.f, 0.f, 0.f, 0.f};
#pragma unroll
  for (int ks = 0; ks < 4; ++ks) {
    short8 af[4];
#pragma unroll
    for (int ti = 0; ti < 4; ++ti)
      af[ti] = *(const short8*)&sA[(wy * 64 + ti * 16 + ln) * 136 + ks * 32 + qd * 8];
#pragma unroll
    for (int tj = 0; tj < 4; ++tj) {
      short8 bf = *(const short8*)&sB[(wx * 64 + tj * 16 + ln) * 136 + ks * 32 + qd * 8];
#pragma unroll
      for (int ti = 0; ti < 4; ++ti)
        acc1[ti][tj] = __builtin_amdgcn_mfma_f32_16x16x32_bf16(af[ti], bf, acc1[ti][tj], 0, 0, 0);
    }
  }
  __syncthreads();

  // P write (swizzled): shorts offset p*1032 + d*32 + ((cb8^(d&3))*8) + (c&7)
#pragma unroll
  for (int ti = 0; ti < 4; ++ti) {
    int m0 = wy * 64 + ti * 16;
    int iloc = m0 >> 5;
    int cbase = (m0 & 31) + qd * 4;
    int cb8 = cbase >> 3;
#pragma unroll
    for (int tj = 0; tj < 4; ++tj) {
      int n0 = wx * 64 + tj * 16;
      int jloc = n0 >> 5;
      int d = (n0 & 31) + ln;
      int p = iloc * 8 + jloc;
      ushort4 h;
      h.x = f2bf(acc1[ti][tj][0]);
      h.y = f2bf(acc1[ti][tj][1]);
      h.z = f2bf(acc1[ti][tj][2]);
      h.w = f2bf(acc1[ti][tj][3]);
      *(ushort4*)&sP[p * 1032 + d * 32 + ((cb8 ^ (d & 3)) * 8) + (cbase & 7)] = h;
    }
  }
  __syncthreads();

  // phase 2: wave job = (zt2 = ww&3 -> zt in {2*zt2, 2*zt2+1}; ksq = ww>>2 -> 8 ks)
  int zt2 = ww & 3, ksq = ww >> 2;
  f32x4 acc2[4][2];
#pragma unroll
  for (int mt = 0; mt < 4; ++mt)
#pragma unroll
    for (int h2 = 0; h2 < 2; ++h2) acc2[mt][h2] = (f32x4){0.f, 0.f, 0.f, 0.f};
#pragma unroll
  for (int kk = 0; kk < 8; ++kk) {
    int ks = ksq * 8 + kk;
    short8 bfr[2];
#pragma unroll
    for (int h2 = 0; h2 < 2; ++h2)
      bfr[h2] = *(const short8*)(WF + ((size_t)((zt2 * 2 + h2) * 32 + ks) * 64 + lane) * 8);
    short8 afr[4];
#pragma unroll
    for (int mt = 0; mt < 4; ++mt)
      afr[mt] = *(const short8*)&sP[(mt * 16 + ln) * 1032 + ks * 32 + ((qd ^ (ks & 3)) * 8)];
#pragma unroll
    for (int mt = 0; mt < 4; ++mt)
#pragma unroll
      for (int h2 = 0; h2 < 2; ++h2)
        acc2[mt][h2] = __builtin_amdgcn_mfma_f32_16x16x32_bf16(afr[mt], bfr[h2], acc2[mt][h2], 0, 0, 0);
  }

  // tree-reduce the 4 K-quarter partials per zt2. red[zt2][b][p][zl], stride 33 f32.
  __syncthreads();   // all sP reads done; safe to overwrite
  if (ksq >= 2) {
#pragma unroll
    for (int mt = 0; mt < 4; ++mt)
#pragma unroll
      for (int h2 = 0; h2 < 2; ++h2)
#pragma unroll
        for (int rg = 0; rg < 4; ++rg) {
          int p = mt * 16 + qd * 4 + rg, zl = h2 * 16 + ln;
          redF[((zt2 * 2 + (ksq - 2)) * 64 + p) * 33 + zl] = acc2[mt][h2][rg];
        }
  }
  __syncthreads();
  if (ksq < 2) {
#pragma unroll
    for (int mt = 0; mt < 4; ++mt)
#pragma unroll
      for (int h2 = 0; h2 < 2; ++h2)
#pragma unroll
        for (int rg = 0; rg < 4; ++rg) {
          int p = mt * 16 + qd * 4 + rg, zl = h2 * 16 + ln;
          acc2[mt][h2][rg] += redF[((zt2 * 2 + ksq) * 64 + p) * 33 + zl];
        }
    if (ksq == 1) {
#pragma unroll
      for (int mt = 0; mt < 4; ++mt)
#pragma unroll
        for (int h2 = 0; h2 < 2; ++h2)
#pragma unroll
          for (int rg = 0; rg < 4; ++rg) {
            int p = mt * 16 + qd * 4 + rg, zl = h2 * 16 + ln;
            redF[((zt2 * 2 + 1) * 64 + p) * 33 + zl] = acc2[mt][h2][rg];
          }
    }
  }
  __syncthreads();
  if (ksq == 0) {
#pragma unroll
    for (int mt = 0; mt < 4; ++mt)
#pragma unroll
      for (int h2 = 0; h2 < 2; ++h2) {
        int z = (zt2 * 2 + h2) * 16 + ln;
        float bz = bout[z];
#pragma unroll
        for (int rg = 0; rg < 4; ++rg) {
          int p = mt * 16 + qd * 4 + rg, zl = h2 * 16 + ln;
          float v = acc2[mt][h2][rg] + redF[((zt2 * 2 + 1) * 64 + p) * 33 + zl] + bz;
          int i = i0 + (p >> 3), j = j0 + (p & 7);
          out[((size_t)i * IDIM + j) * CZ + z] = v;
        }
      }
  }
}

extern "C" void kernel_launch(void* const* d_in, const int* in_sizes, int n_in,
                              void* d_out, int out_size, void* d_ws, size_t ws_size,
                              hipStream_t stream) {
  const float* msa = (const float*)d_in[0];
  const float* lnw = (const float*)d_in[1];
  const float* lnb = (const float*)d_in[2];
  const float* wl  = (const float*)d_in[3];
  const float* bl  = (const float*)d_in[4];
  const float* wr  = (const float*)d_in[5];
  const float* br  = (const float*)d_in[6];
  const float* wo  = (const float*)d_in[7];
  const float* bo  = (const float*)d_in[8];
  float* out = (float*)d_out;

  char* ws = (char*)d_ws;
  unsigned short* Abuf = (unsigned short*)ws;                         // 2 MB
  unsigned short* Bbuf = (unsigned short*)(ws + (2u << 20));          // 2 MB
  unsigned short* wlrT = (unsigned short*)(ws + (4u << 20));          // 32 KB
  unsigned short* WF   = (unsigned short*)(ws + (4u << 20) + 32768);  // 256 KB

  (void)hipFuncSetAttribute((const void*)k_main,
                            hipFuncAttributeMaxDynamicSharedMemorySize, 139264);
  (void)hipFuncSetAttribute((const void*)k_lnproj,
                            hipFuncAttributeMaxDynamicSharedMemorySize, 84992);

  k_prep<<<128, 256, 0, stream>>>(wl, wr, wo, wlrT, WF);
  k_lnproj<<<256, 512, 84992, stream>>>(msa, lnw, lnb, bl, br, wlrT, Abuf, Bbuf);
  k_main<<<dim3(32, 32), 1024, 139264, stream>>>(Abuf, Bbuf, WF, bo, out);
}

// Round 5
// 152.182 us; speedup vs baseline: 1.6549x; 1.0243x over previous
//
#include <hip/hip_runtime.h>

typedef __attribute__((ext_vector_type(8))) short short8;
typedef __attribute__((ext_vector_type(4))) float f32x4;

#define CM 256
#define CC 32
#define CZ 128
#define SDIM 128
#define IDIM 256

__device__ __forceinline__ unsigned short f2bf(float f) {
  union { float f; unsigned u; } v; v.f = f;
  unsigned r = v.u + 0x7fffu + ((v.u >> 16) & 1u);
  return (unsigned short)(r >> 16);
}

// ---------------- kernel 0: weight prep ----------------
// wlrT[c64][e]  (c64<32: w_left col, else w_right col), bf16, [64][256]
// WF = W_out fragment-major: WF[((zt*32+ks)*64 + lane)*8 + e]
//   lane=(qd*16+ln) holds W[z=zt*16+ln][kappa=ks*32+qd*8+e]/128, kappa=d*32+c (d=ks, c=qd*8+e)
__global__ void k_prep(const float* __restrict__ wl, const float* __restrict__ wr,
                       const float* __restrict__ wo,
                       unsigned short* __restrict__ wlrT, unsigned short* __restrict__ WF) {
  int t = blockIdx.x * 256 + threadIdx.x;
  if (t < 64 * 256) {
    int c = t >> 8, e = t & 255;
    float v = (c < CC) ? wl[e * CC + c] : wr[e * CC + (c - CC)];
    wlrT[c * 256 + e] = f2bf(v);
  } else {
    int t2 = t - 64 * 256;
    if (t2 < 8 * 32 * 64) {
      int zt = t2 >> 11, ks = (t2 >> 6) & 31, lane = t2 & 63;
      int ln = lane & 15, qd = lane >> 4;
      int z = zt * 16 + ln;
#pragma unroll
      for (int e = 0; e < 8; ++e) {
        int c = qd * 8 + e, d = ks;
        WF[(size_t)t2 * 8 + e] = f2bf(wo[(c * 32 + d) * CZ + z] * (1.0f / 128.0f));
      }
    }
  }
}

// ---------------- kernel 1: LayerNorm + dual projection ----------------
// One block per i (256 blocks x 512 threads). Outputs:
//   A2 fragment-major: A2[((rt*4+ks)*64+lane)*8+e] = A[rt*16+ln][ks*32+qd*8+e]  (rt = Arow/16)
//   Bbuf row-major:    Bbuf[(i*32+d)*128 + s]
__global__ __launch_bounds__(512) void k_lnproj(
    const float* __restrict__ x, const float* __restrict__ lnw, const float* __restrict__ lnb,
    const float* __restrict__ bl, const float* __restrict__ br,
    const unsigned short* __restrict__ wlrT,
    unsigned short* __restrict__ A2, unsigned short* __restrict__ Bbuf) {
  extern __shared__ __align__(16) char lds[];
  unsigned short* xn = (unsigned short*)lds;            // [128 s][264] = 67,584 B
  unsigned short* sT = (unsigned short*)(lds + 67584);  // [64 c64][136] = 17,408 B
  int tid = threadIdx.x;
  int lane = tid & 63, ww = tid >> 6;      // 8 waves
  int qd = lane >> 4, ln = lane & 15;
  int i = blockIdx.x;

  // LN: wave ww handles s = ww*16 .. +15
  for (int rr = 0; rr < 16; ++rr) {
    int s = ww * 16 + rr;
    float4 v = ((const float4*)(x + ((size_t)s * IDIM + i) * CM))[lane];
    float s1 = v.x + v.y + v.z + v.w;
    float s2 = v.x * v.x + v.y * v.y + v.z * v.z + v.w * v.w;
#pragma unroll
    for (int off = 32; off; off >>= 1) {
      s1 += __shfl_xor(s1, off);
      s2 += __shfl_xor(s2, off);
    }
    float mu = s1 * (1.0f / 256.0f);
    float var = s2 * (1.0f / 256.0f) - mu * mu;
    float rs = rsqrtf(var + 1e-5f);
    float4 w4 = ((const float4*)lnw)[lane];
    float4 b4 = ((const float4*)lnb)[lane];
    ushort4 h;
    h.x = f2bf((v.x - mu) * rs * w4.x + b4.x);
    h.y = f2bf((v.y - mu) * rs * w4.y + b4.y);
    h.z = f2bf((v.z - mu) * rs * w4.z + b4.z);
    h.w = f2bf((v.w - mu) * rs * w4.w + b4.w);
    *(ushort4*)&xn[s * 264 + lane * 4] = h;
  }
  __syncthreads();

  // project: wave ww = m-tile (16 s-rows), all 4 n-tiles, K=256
  f32x4 acc[4];
#pragma unroll
  for (int nt = 0; nt < 4; ++nt) acc[nt] = (f32x4){0.f, 0.f, 0.f, 0.f};
#pragma unroll
  for (int ks = 0; ks < 8; ++ks) {
    short8 af = *(const short8*)&xn[(ww * 16 + ln) * 264 + ks * 32 + qd * 8];
#pragma unroll
    for (int nt = 0; nt < 4; ++nt) {
      short8 bf = *(const short8*)(wlrT + (nt * 16 + ln) * 256 + ks * 32 + qd * 8);
      acc[nt] = __builtin_amdgcn_mfma_f32_16x16x32_bf16(af, bf, acc[nt], 0, 0, 0);
    }
  }
  // C layout: col(c64)=ln, row(s-local)=qd*4+rg. Add bias, transpose via sT[c64][s].
#pragma unroll
  for (int nt = 0; nt < 4; ++nt) {
    int c64 = nt * 16 + ln;
    float bias = (c64 < CC) ? bl[c64] : br[c64 - CC];
    ushort4 h;
    h.x = f2bf(acc[nt][0] + bias);
    h.y = f2bf(acc[nt][1] + bias);
    h.z = f2bf(acc[nt][2] + bias);
    h.w = f2bf(acc[nt][3] + bias);
    *(ushort4*)&sT[c64 * 136 + ww * 16 + qd * 4] = h;
  }
  __syncthreads();

  // A2 fragment store: wave job (rtloc = ww>>2, ks4 = ww&3); rt = 2*i + rtloc
  {
    int rtloc = ww >> 2, ks4 = ww & 3;
    short8 v = *(const short8*)&sT[(rtloc * 16 + ln) * 136 + ks4 * 32 + qd * 8];
    *(short8*)(A2 + ((size_t)(((2 * i + rtloc) * 4 + ks4) * 64 + lane)) * 8) = v;
  }
  // B row-major store: 32 rows x 16 chunks, 1 chunk/thread
  {
    int row = tid >> 4, ch = tid & 15;
    short8 v = *(const short8*)&sT[(CC + row) * 136 + ch * 8];
    *(short8*)(Bbuf + ((size_t)(i * CC + row)) * SDIM + ch * 8) = v;
  }
}

// ---------------- kernel 2: fused outer-product + output projection ----------------
// Block = 8i x 4j = 32 pairs, 512 threads (8 waves), LDS 34.8 KB -> 2 blocks/CU.
// p1: P[256][128] = A@B^T (K=128); A-frags from global A2, B-frags from LDS sB.
// sP materialized in two K-halves (d<16 / d>=16) overlaying sB; p2 on waves 0-3
// (zth x kq jobs, acc carried over both halves), 1 LDS f32 merge, store.
__global__ __launch_bounds__(512, 4) void k_main(
    const unsigned short* __restrict__ A2, const unsigned short* __restrict__ Bbuf,
    const unsigned short* __restrict__ WF, const float* __restrict__ bout,
    float* __restrict__ out) {
  extern __shared__ __align__(16) char lds[];
  unsigned short* sB = (unsigned short*)lds;   // [128][136] = 34,816 B
  unsigned short* sP = (unsigned short*)lds;   // [32][520]  = 33,280 B (overlay)
  float* redF = (float*)lds;                   // [64][68] f32 = 17,408 B (overlay)
  int tid = threadIdx.x;
  int lane = tid & 63, ww = tid >> 6;
  int qd = lane >> 4, ln = lane & 15;
  int i0 = blockIdx.x * 8, j0 = blockIdx.y * 4;

  // stage B tile: rows j0*32 .. +127, K=128
#pragma unroll
  for (int t = 0; t < 4; ++t) {
    int idx = tid + t * 512;
    int r = idx >> 4, ch = idx & 15;
    short8 v = *(const short8*)(Bbuf + (size_t)(j0 * CC + r) * SDIM + ch * 8);
    *(short8*)&sB[r * 136 + ch * 8] = v;
  }
  __syncthreads();

  // phase 1: wave (wy = ww>>1, wx = ww&1) computes 64x64 region (4x4 16x16 tiles)
  int wy = ww >> 1, wx = ww & 1;
  f32x4 acc1[4][4];
#pragma unroll
  for (int a = 0; a < 4; ++a)
#pragma unroll
    for (int b = 0; b < 4; ++b) acc1[a][b] = (f32x4){0.f, 0.f, 0.f, 0.f};
#pragma unroll
  for (int ks = 0; ks < 4; ++ks) {
    short8 af[4];
#pragma unroll
    for (int ti = 0; ti < 4; ++ti)
      af[ti] = *(const short8*)(A2 + ((size_t)((i0 * 2 + wy * 4 + ti) * 4 + ks) * 64 + lane) * 8);
#pragma unroll
    for (int tj = 0; tj < 4; ++tj) {
      short8 bf = *(const short8*)&sB[(wx * 64 + tj * 16 + ln) * 136 + ks * 32 + qd * 8];
#pragma unroll
      for (int ti = 0; ti < 4; ++ti)
        acc1[ti][tj] = __builtin_amdgcn_mfma_f32_16x16x32_bf16(af[ti], bf, acc1[ti][tj], 0, 0, 0);
    }
  }

  // two K-half passes: P(d-half) -> sP -> p2 accumulate
  f32x4 acc2[2][4];
#pragma unroll
  for (int mt = 0; mt < 2; ++mt)
#pragma unroll
    for (int z4 = 0; z4 < 4; ++z4) acc2[mt][z4] = (f32x4){0.f, 0.f, 0.f, 0.f};

  for (int h = 0; h < 2; ++h) {
    __syncthreads();  // h=0: all sB reads done; h=1: all p2(h0) sP reads done
    // write P half: tj in {h, h+2} have d = 16*(tj&1)+ln -> d-half h. dh = ln.
    // swizzle: chunk slot = ((dh>>1)&3) ^ cb  (2-way max on write and read)
#pragma unroll
    for (int ti = 0; ti < 4; ++ti) {
      int iloc = 2 * wy + (ti >> 1);
      int cbase = 16 * (ti & 1) + qd * 4;
      int cb = cbase >> 3;
#pragma unroll
      for (int u = 0; u < 2; ++u) {
        int tj = h + u * 2;
        int jloc = 2 * wx + (tj >> 1);
        int p = iloc * 4 + jloc;
        ushort4 hh;
        hh.x = f2bf(acc1[ti][tj][0]);
        hh.y = f2bf(acc1[ti][tj][1]);
        hh.z = f2bf(acc1[ti][tj][2]);
        hh.w = f2bf(acc1[ti][tj][3]);
        *(ushort4*)&sP[p * 520 + ln * 32 + ((((ln >> 1) & 3) ^ cb) * 8) + (cbase & 7)] = hh;
      }
    }
    __syncthreads();
    // p2 half (waves 0..3): wave = (zth = ww&1 -> 4 zt) x (kq = ww>>1 -> 8 ks'), both mt
    if (ww < 4) {
      int zth = ww & 1, kq = ww >> 1;
#pragma unroll
      for (int kk = 0; kk < 8; ++kk) {
        int ksp = kq * 8 + kk;          // ks' in [0,16) within half
        int gks = h * 16 + ksp;         // global 32-chunk index in [0,32)
        short8 afr[2];
#pragma unroll
        for (int mt = 0; mt < 2; ++mt)
          afr[mt] = *(const short8*)&sP[(mt * 16 + ln) * 520 + ksp * 32 + ((((ksp >> 1) & 3) ^ qd) * 8)];
#pragma unroll
        for (int z4 = 0; z4 < 4; ++z4) {
          int zt = zth * 4 + z4;
          short8 bfr = *(const short8*)(WF + ((size_t)(zt * 32 + gks) * 64 + lane) * 8);
#pragma unroll
          for (int mt = 0; mt < 2; ++mt)
            acc2[mt][z4] = __builtin_amdgcn_mfma_f32_16x16x32_bf16(afr[mt], bfr, acc2[mt][z4], 0, 0, 0);
        }
      }
    }
  }

  __syncthreads();  // p2(h1) sP reads done; redF overlay safe
  if (ww == 2 || ww == 3) {   // kq==1 partials -> LDS
    int zth = ww & 1;
#pragma unroll
    for (int mt = 0; mt < 2; ++mt)
#pragma unroll
      for (int z4 = 0; z4 < 4; ++z4)
#pragma unroll
        for (int rg = 0; rg < 4; ++rg) {
          int p = mt * 16 + qd * 4 + rg;
          redF[(zth * 32 + p) * 68 + z4 * 16 + ln] = acc2[mt][z4][rg];
        }
  }
  __syncthreads();
  if (ww == 0 || ww == 1) {   // kq==0: merge + bias + store
    int zth = ww & 1;
#pragma unroll
    for (int mt = 0; mt < 2; ++mt)
#pragma unroll
      for (int z4 = 0; z4 < 4; ++z4) {
        int z = (zth * 4 + z4) * 16 + ln;
        float bz = bout[z];
#pragma unroll
        for (int rg = 0; rg < 4; ++rg) {
          int p = mt * 16 + qd * 4 + rg;
          float v = acc2[mt][z4][rg] + redF[(zth * 32 + p) * 68 + z4 * 16 + ln] + bz;
          out[((size_t)(i0 + (p >> 2)) * IDIM + (j0 + (p & 3))) * CZ + z] = v;
        }
      }
  }
}

extern "C" void kernel_launch(void* const* d_in, const int* in_sizes, int n_in,
                              void* d_out, int out_size, void* d_ws, size_t ws_size,
                              hipStream_t stream) {
  const float* msa = (const float*)d_in[0];
  const float* lnw = (const float*)d_in[1];
  const float* lnb = (const float*)d_in[2];
  const float* wl  = (const float*)d_in[3];
  const float* bl  = (const float*)d_in[4];
  const float* wr  = (const float*)d_in[5];
  const float* br  = (const float*)d_in[6];
  const float* wo  = (const float*)d_in[7];
  const float* bo  = (const float*)d_in[8];
  float* out = (float*)d_out;

  char* ws = (char*)d_ws;
  unsigned short* A2   = (unsigned short*)ws;                         // 2 MB (frag-major)
  unsigned short* Bbuf = (unsigned short*)(ws + (2u << 20));          // 2 MB (row-major)
  unsigned short* wlrT = (unsigned short*)(ws + (4u << 20));          // 32 KB
  unsigned short* WF   = (unsigned short*)(ws + (4u << 20) + 32768);  // 256 KB

  (void)hipFuncSetAttribute((const void*)k_lnproj,
                            hipFuncAttributeMaxDynamicSharedMemorySize, 84992);

  k_prep<<<128, 256, 0, stream>>>(wl, wr, wo, wlrT, WF);
  k_lnproj<<<256, 512, 84992, stream>>>(msa, lnw, lnb, bl, br, wlrT, A2, Bbuf);
  k_main<<<dim3(32, 64), 512, 34816, stream>>>(A2, Bbuf, WF, bo, out);
}